// Round 14
// baseline (47.221 us; speedup 1.0000x reference)
//
#include <hip/hip_runtime.h>

// VQ-VAE quantizer: x[32][64][64][64] f32 NCHW, embed[1024][64] f32
// out: z_q (8388608 f32, NCHW) ++ loss (1 f32),  loss = 1.25*mean((z_q-z)^2)
//
// R14 = R9 champion structure (512 thr / 8 waves / 256 pos per block, whole
// fp8 codebook LDS-resident, zero-barrier sweep, packed-u32 argmax keys,
// loss-from-keys) with three taxes removed:
//  - SINGLE kernel: each block converts embed f32 (L2-hot) -> fp8 LDS itself;
//    prep launch + eb/c0 workspace round-trip deleted. Loss zeroed by
//    hipMemsetAsync.
//  - 72-B LDS row stride: a0/a1 ds_read_b64 banks = (18*l15+2*lq)%32 -> exactly
//    4 accesses/bank = the 512B/wave floor (64-B stride was 2x over floor).
//  - linear slot layout (no XOR swizzle anywhere).
// argmin dist == argmax acc (acc = z.(1024e) + 64 - 512||e||^2 in (9,119) > 0);
// key = (bits(acc) & ~1023) | (1023 - code): u32 max = argmin + smallest-index
// tie-break. NO launch_bounds (R3/R5/R11: every forced bound spilled).

#define TOTAL_ELEMS 8388608
#define LOSS_SCALE (1.25f / 8388608.f)
#define ROWB 72   // LDS bytes per codebook row (64 data + 8 pad)

typedef float  f32x4 __attribute__((ext_vector_type(4)));
typedef unsigned int u32x4 __attribute__((ext_vector_type(4)));

static __device__ __forceinline__ unsigned int umax(unsigned int a, unsigned int b) {
    return a > b ? a : b;
}
static __device__ __forceinline__ float dot4(f32x4 v) {
    return v[0]*v[0] + v[1]*v[1] + v[2]*v[2] + v[3]*v[3];
}

// block = 512 thr = 8 waves; wave = 32 positions (nt=2): h-row wv>>1, w-half wv&1
// grid 512 = 32 b x 16 h-groups (4 rows)
__global__ void vq_main(
    const float* __restrict__ x,
    const float* __restrict__ embed,            // f32 (conversion + exact gather)
    float* __restrict__ out,
    float* __restrict__ loss) {

    __shared__ __align__(16) unsigned char cb[1024 * ROWB]; // fp8 codebook, 72 KB
    __shared__ __align__(16) float c0l[1024];
    __shared__ float lpart[8];

    const int t    = threadIdx.x;
    const int wv   = t >> 6, lane = t & 63;
    const int l15  = lane & 15, lq = lane >> 4;

    const int blk = blockIdx.x;                  // 0..511
    const int b   = blk >> 4;
    const int h0  = (blk & 15) * 4;
    const size_t xbase = (size_t)b * 262144 + (size_t)h0 * 64;
    const int rowoff = (wv >> 1) * 64 + (wv & 1) * 32;   // wave's pos offset in tile

    // ---- codebook conversion: thread t -> rows t, t+512 (embed L2-hot) ----
#pragma unroll
    for (int rr = 0; rr < 2; rr++) {
        const int r = t + rr * 512;
        const float* er = embed + r * 64;
        float s = 0.f;
#pragma unroll
        for (int p = 0; p < 4; p++) {
            f32x4 v0 = *(const f32x4*)(er + p * 16);
            f32x4 v1 = *(const f32x4*)(er + p * 16 + 4);
            f32x4 v2 = *(const f32x4*)(er + p * 16 + 8);
            f32x4 v3 = *(const f32x4*)(er + p * 16 + 12);
            s += dot4(v0) + dot4(v1) + dot4(v2) + dot4(v3);
            unsigned int d0 = 0, d1 = 0, d2 = 0, d3 = 0;
            d0 = __builtin_amdgcn_cvt_pk_fp8_f32(v0[0]*1024.f, v0[1]*1024.f, d0, false);
            d0 = __builtin_amdgcn_cvt_pk_fp8_f32(v0[2]*1024.f, v0[3]*1024.f, d0, true);
            d1 = __builtin_amdgcn_cvt_pk_fp8_f32(v1[0]*1024.f, v1[1]*1024.f, d1, false);
            d1 = __builtin_amdgcn_cvt_pk_fp8_f32(v1[2]*1024.f, v1[3]*1024.f, d1, true);
            d2 = __builtin_amdgcn_cvt_pk_fp8_f32(v2[0]*1024.f, v2[1]*1024.f, d2, false);
            d2 = __builtin_amdgcn_cvt_pk_fp8_f32(v2[2]*1024.f, v2[3]*1024.f, d2, true);
            d3 = __builtin_amdgcn_cvt_pk_fp8_f32(v3[0]*1024.f, v3[1]*1024.f, d3, false);
            d3 = __builtin_amdgcn_cvt_pk_fp8_f32(v3[2]*1024.f, v3[3]*1024.f, d3, true);
            u32x4 q = {d0, d1, d2, d3};
            *(u32x4*)(&cb[r * ROWB + p * 16]) = q;
        }
        c0l[r] = 64.f - 512.f * s;               // acc = z.(1024e) + c0 in (9,119)
    }

    // ---- z -> fp8 A-frags in registers; sum z^2 on the fly ----
    // lane: positions nt*16+l15 (nt=0,1), channels kh*32+lq*8+p*4+j
    float part = 0.f;
    long bfr[2][2];
#pragma unroll
    for (int nt = 0; nt < 2; nt++) {
#pragma unroll
        for (int kh = 0; kh < 2; kh++) {
            unsigned int dw[2];
#pragma unroll
            for (int p = 0; p < 2; p++) {
                float f[4];
#pragma unroll
                for (int j = 0; j < 4; j++) {
                    f[j] = x[xbase + (size_t)(kh * 32 + lq * 8 + p * 4 + j) * 4096
                             + (size_t)rowoff + nt * 16 + l15];
                    part += f[j] * f[j];
                }
                unsigned int r = 0;
                r = __builtin_amdgcn_cvt_pk_fp8_f32(f[0], f[1], r, false);
                r = __builtin_amdgcn_cvt_pk_fp8_f32(f[2], f[3], r, true);
                dw[p] = r;
            }
            bfr[nt][kh] = (long)(((unsigned long long)dw[1] << 32) | dw[0]);
        }
    }
    __syncthreads();                             // codebook + c0l ready

    // ---- free-running sweep: 64 code-tiles, no barriers ----
    // lane (l15=code-in-tile row, lq=k-octet): a0 = k[lq*8..+8], a1 = k[32+lq*8..+8]
    unsigned int key[2] = {0u, 0u};
    const unsigned char* bbase = &cb[l15 * ROWB + lq * 8];
    const float* cbase = c0l + lq * 4;
#pragma unroll 8
    for (int mt = 0; mt < 64; mt++) {
        long a0 = *(const long*)(bbase + mt * 16 * ROWB);
        long a1 = *(const long*)(bbase + mt * 16 * ROWB + 32);
        f32x4 c0v = *(const f32x4*)(cbase + mt * 16);      // broadcast read
        const int invm = 1023 - mt * 16 - lq * 4;
#pragma unroll
        for (int nt = 0; nt < 2; nt++) {
            f32x4 acc = __builtin_amdgcn_mfma_f32_16x16x32_fp8_fp8(
                a0, bfr[nt][0], c0v, 0, 0, 0);
            acc = __builtin_amdgcn_mfma_f32_16x16x32_fp8_fp8(
                a1, bfr[nt][1], acc, 0, 0, 0);
            // D: col(l15)=pos-in-16-tile, row=(lq*4+r)=code-in-16-tile
            unsigned int k0 = (__float_as_uint(acc[0]) & 0xFFFFFC00u) | (unsigned int)(invm);
            unsigned int k1 = (__float_as_uint(acc[1]) & 0xFFFFFC00u) | (unsigned int)(invm - 1);
            unsigned int k2 = (__float_as_uint(acc[2]) & 0xFFFFFC00u) | (unsigned int)(invm - 2);
            unsigned int k3 = (__float_as_uint(acc[3]) & 0xFFFFFC00u) | (unsigned int)(invm - 3);
            key[nt] = umax(key[nt], umax(umax(k0, k1), umax(k2, k3)));
        }
    }

    // ---- reduce lq replicas; every lane ends with both final keys ----
#pragma unroll
    for (int nt = 0; nt < 2; nt++) {
        unsigned int k = key[nt];
        unsigned int o = (unsigned int)__shfl_xor((int)k, 16); k = umax(k, o);
        o = (unsigned int)__shfl_xor((int)k, 32);              k = umax(k, o);
        key[nt] = k;
        // winning acc appears on 4 lq-replica lanes: dist = ||z||^2 - acc/512
        // + 0.125 -> subtract acc/(4*512) per replica
        part -= (1.f / 2048.f) * __uint_as_float(k & 0xFFFFFC00u);
    }

    // ---- this lane's own position: pos = lane&31 -> nt = (lane>>4)&1 ----
    unsigned int ks = ((lane >> 4) & 1) ? key[1] : key[0];
    const int idx = 1023 - (int)(ks & 1023u);

    // ---- loss wave-reduce ----
#pragma unroll
    for (int off = 1; off < 64; off <<= 1) part += __shfl_xor(part, off);
    if (lane == 0) lpart[wv] = part;

    // ---- epilogue: z_q gather (exact f32; idx fixed per thread), stores are
    //      2x128B contiguous segments per instruction ----
    const int ch0 = (lane >> 5) * 32;            // channel half
    const int pos = lane & 31;
    const float* erow = embed + idx * 64 + ch0;
    float* orow = out + xbase + (size_t)rowoff + pos + (size_t)ch0 * 4096;
#pragma unroll
    for (int c4 = 0; c4 < 8; c4++) {
        f32x4 ev = *(const f32x4*)(erow + c4 * 4);
#pragma unroll
        for (int j = 0; j < 4; j++)
            orow[(size_t)(c4 * 4 + j) * 4096] = ev[j];
    }

    __syncthreads();                             // lpart visible
    if (t == 0) {
        float s = lpart[0] + lpart[1] + lpart[2] + lpart[3]
                + lpart[4] + lpart[5] + lpart[6] + lpart[7];
        // sum_p dist = sum(z^2) - sum(acc)/512 + 0.125*256
        atomicAdd(loss, (s + 32.0f) * LOSS_SCALE);
    }
}

extern "C" void kernel_launch(void* const* d_in, const int* in_sizes, int n_in,
                              void* d_out, int out_size, void* d_ws, size_t ws_size,
                              hipStream_t stream) {
    const float* x     = (const float*)d_in[0];
    const float* embed = (const float*)d_in[1];
    float* out  = (float*)d_out;
    float* loss = out + TOTAL_ELEMS;

    hipMemsetAsync(loss, 0, sizeof(float), stream);   // graph-safe (memset node)
    vq_main<<<512, 512, 0, stream>>>(x, embed, out, loss);
}

// Round 15
// 35.427 us; speedup vs baseline: 1.3329x; 1.3329x over previous
//
#include <hip/hip_runtime.h>

// VQ-VAE quantizer: x[32][64][64][64] f32 NCHW, embed[1024][64] f32
// out: z_q (8388608 f32, NCHW) ++ loss (1 f32),  loss = 1.25*mean((z_q-z)^2)
//
// R15 = R9 champion (prep kernel + 512thr/8wave main, whole fp8 codebook
// LDS-resident via global_load_lds, zero-barrier sweep, packed-u32 argmax
// keys, loss-from-keys, launch_bounds(512,4)) + the ONE fix R14 validated:
// 72-B LDS row stride (linear, no XOR): a0/a1 ds_read_b64 banks =
// (18*l15+2*lq)%32 -> exactly 4 touches/bank = the 512B/wave floor. R9's
// 64-B XOR layout was ~8-way conflicted (<=16 distinct banks).
// acc = z.(1024e) + 64 - 512||e||^2 in (9,119) > 0; key =
// (bits(acc) & ~1023) | (1023-code): u32 max = argmin dist + smallest-index
// tie-break.

#define TOTAL_ELEMS 8388608
#define LOSS_SCALE (1.25f / 8388608.f)
#define ROWB 72   // eb/LDS bytes per codebook row (64 data + 8 pad)

typedef float f32x4 __attribute__((ext_vector_type(4)));

static __device__ __forceinline__ void gload_lds16(const void* g, void* l) {
    __builtin_amdgcn_global_load_lds(
        (const __attribute__((address_space(1))) void*)g,
        (__attribute__((address_space(3))) void*)l,
        16, 0, 0);
}

static __device__ __forceinline__ unsigned int umax(unsigned int a, unsigned int b) {
    return a > b ? a : b;
}

// ---- prep: embed f32 -> fp8 e4m3 (x1024; unscaled values are subnormal-
// flushed), rows at 72-B stride (linear layout, pad unused);
// c0 = 64 - 512*||e||^2 ----
__global__ void vq_prep(const float* __restrict__ embed,
                        unsigned char* __restrict__ eb,
                        float* __restrict__ c0,
                        float* __restrict__ loss_slot) {
    int t   = blockIdx.x * 256 + threadIdx.x;   // 0..4095
    int row = t >> 2, qd = t & 3;               // qd = k-octet (lq)
    const float* s0 = embed + row * 64 + qd * 8;        // k = qd*8 .. +8
    const float* s1 = embed + row * 64 + 32 + qd * 8;   // k = 32+qd*8 .. +8
    f32x4 v0 = *(const f32x4*)s0, v1 = *(const f32x4*)(s0 + 4);
    f32x4 w0 = *(const f32x4*)s1, w1 = *(const f32x4*)(s1 + 4);
    float s = v0[0]*v0[0] + v0[1]*v0[1] + v0[2]*v0[2] + v0[3]*v0[3]
            + v1[0]*v1[0] + v1[1]*v1[1] + v1[2]*v1[2] + v1[3]*v1[3]
            + w0[0]*w0[0] + w0[1]*w0[1] + w0[2]*w0[2] + w0[3]*w0[3]
            + w1[0]*w1[0] + w1[1]*w1[1] + w1[2]*w1[2] + w1[3]*w1[3];
    unsigned int d0 = 0, d1 = 0, d2 = 0, d3 = 0;
    d0 = __builtin_amdgcn_cvt_pk_fp8_f32(v0[0]*1024.f, v0[1]*1024.f, d0, false);
    d0 = __builtin_amdgcn_cvt_pk_fp8_f32(v0[2]*1024.f, v0[3]*1024.f, d0, true);
    d1 = __builtin_amdgcn_cvt_pk_fp8_f32(v1[0]*1024.f, v1[1]*1024.f, d1, false);
    d1 = __builtin_amdgcn_cvt_pk_fp8_f32(v1[2]*1024.f, v1[3]*1024.f, d1, true);
    d2 = __builtin_amdgcn_cvt_pk_fp8_f32(w0[0]*1024.f, w0[1]*1024.f, d2, false);
    d2 = __builtin_amdgcn_cvt_pk_fp8_f32(w0[2]*1024.f, w0[3]*1024.f, d2, true);
    d3 = __builtin_amdgcn_cvt_pk_fp8_f32(w1[0]*1024.f, w1[1]*1024.f, d3, false);
    d3 = __builtin_amdgcn_cvt_pk_fp8_f32(w1[2]*1024.f, w1[3]*1024.f, d3, true);
    unsigned long long g0 = (unsigned long long)d0 | ((unsigned long long)d1 << 32);
    unsigned long long g1 = (unsigned long long)d2 | ((unsigned long long)d3 << 32);
    char* rb = (char*)eb + row * ROWB;          // 8-B aligned (72 = 9*8)
    *(unsigned long long*)(rb + qd * 8)      = g0;   // k[qd*8..+8]
    *(unsigned long long*)(rb + 32 + qd * 8) = g1;   // k[32+qd*8..+8]
    s += __shfl_xor(s, 1);
    s += __shfl_xor(s, 2);
    if (qd == 0) c0[row] = 64.f - 512.f * s;    // acc = z.(1024e) + c0, in (9,119)
    if (t == 0) *loss_slot = 0.f;
}

// block = 512 thr = 8 waves; wave = 32 positions (nt=2): h-row wv>>1, w-half wv&1
// grid 512 = 32 b x 16 h-groups; 2 blocks/CU (LDS ~78 KB)
__global__ __launch_bounds__(512, 4) void vq_main(
    const float* __restrict__ x,
    const float* __restrict__ embed,            // f32, for exact gather
    const unsigned char* __restrict__ eb,       // fp8 rows @ 72-B stride (72 KB)
    const float* __restrict__ c0,               // f32 per-code C-init
    float* __restrict__ out,
    float* __restrict__ loss) {

    __shared__ __align__(16) unsigned char cb[1024 * ROWB]; // 72 KB
    __shared__ __align__(16) float c0l[1024];
    __shared__ float lpart[8];

    const int t    = threadIdx.x;
    const int wv   = t >> 6, lane = t & 63;
    const int l15  = lane & 15, lq = lane >> 4;

    const int blk = blockIdx.x;                  // 0..511
    const int b   = blk >> 4;
    const int h0  = (blk & 15) * 4;
    const size_t xbase = (size_t)b * 262144 + (size_t)h0 * 64;
    const int rowoff = (wv >> 1) * 64 + (wv & 1) * 32;   // wave's pos offset in tile

    const char* ebp = (const char*)eb;

    // ---- codebook DMA (72 KB linear image, async, no VGPRs): 9 x 512 x 16B ----
#pragma unroll
    for (int s = 0; s < 9; s++)
        gload_lds16(ebp + s * 8192 + t * 16, &cb[s * 8192 + t * 16]);

    // ---- c0 -> LDS (4 KB) ----
    if (t < 256) *(f32x4*)(c0l + t * 4) = *(const f32x4*)(c0 + t * 4);

    // ---- z -> fp8 A-frags in registers; sum z^2 on the fly ----
    // lane: positions nt*16+l15 (nt=0,1), channels kh*32+lq*8+p*4+j
    float part = 0.f;
    long bfr[2][2];
#pragma unroll
    for (int nt = 0; nt < 2; nt++) {
#pragma unroll
        for (int kh = 0; kh < 2; kh++) {
            unsigned int dw[2];
#pragma unroll
            for (int p = 0; p < 2; p++) {
                float f[4];
#pragma unroll
                for (int j = 0; j < 4; j++) {
                    f[j] = x[xbase + (size_t)(kh * 32 + lq * 8 + p * 4 + j) * 4096
                             + (size_t)rowoff + nt * 16 + l15];
                    part += f[j] * f[j];
                }
                unsigned int r = 0;
                r = __builtin_amdgcn_cvt_pk_fp8_f32(f[0], f[1], r, false);
                r = __builtin_amdgcn_cvt_pk_fp8_f32(f[2], f[3], r, true);
                dw[p] = r;
            }
            bfr[nt][kh] = (long)(((unsigned long long)dw[1] << 32) | dw[0]);
        }
    }
    __syncthreads();                             // DMA + c0l complete

    // ---- free-running sweep: 64 code-tiles, no barriers ----
    // lane (l15=code-in-tile row, lq=k-octet); banks (18*l15+2*lq)%32 -> 4/bank
    unsigned int key[2] = {0u, 0u};
    const unsigned char* bbase = &cb[l15 * ROWB + lq * 8];
    const float* cbase = c0l + lq * 4;
#pragma unroll 8
    for (int mt = 0; mt < 64; mt++) {
        long a0 = *(const long*)(bbase + mt * 16 * ROWB);        // k[lq*8..+8]
        long a1 = *(const long*)(bbase + mt * 16 * ROWB + 32);   // k[32+lq*8..+8]
        f32x4 c0v = *(const f32x4*)(cbase + mt * 16);            // broadcast read
        const int invm = 1023 - mt * 16 - lq * 4;
#pragma unroll
        for (int nt = 0; nt < 2; nt++) {
            f32x4 acc = __builtin_amdgcn_mfma_f32_16x16x32_fp8_fp8(
                a0, bfr[nt][0], c0v, 0, 0, 0);
            acc = __builtin_amdgcn_mfma_f32_16x16x32_fp8_fp8(
                a1, bfr[nt][1], acc, 0, 0, 0);
            // D: col(l15)=pos-in-16-tile, row=(lq*4+r)=code-in-16-tile
            unsigned int k0 = (__float_as_uint(acc[0]) & 0xFFFFFC00u) | (unsigned int)(invm);
            unsigned int k1 = (__float_as_uint(acc[1]) & 0xFFFFFC00u) | (unsigned int)(invm - 1);
            unsigned int k2 = (__float_as_uint(acc[2]) & 0xFFFFFC00u) | (unsigned int)(invm - 2);
            unsigned int k3 = (__float_as_uint(acc[3]) & 0xFFFFFC00u) | (unsigned int)(invm - 3);
            key[nt] = umax(key[nt], umax(umax(k0, k1), umax(k2, k3)));
        }
    }

    // ---- reduce lq replicas; every lane ends with both final keys ----
#pragma unroll
    for (int nt = 0; nt < 2; nt++) {
        unsigned int k = key[nt];
        unsigned int o = (unsigned int)__shfl_xor((int)k, 16); k = umax(k, o);
        o = (unsigned int)__shfl_xor((int)k, 32);              k = umax(k, o);
        key[nt] = k;
        // winning acc appears on 4 lq-replica lanes: dist = ||z||^2 - acc/512
        // + 0.125 -> subtract acc/(4*512) per replica
        part -= (1.f / 2048.f) * __uint_as_float(k & 0xFFFFFC00u);
    }

    // ---- this lane's own position: pos = lane&31 -> nt = (lane>>4)&1 ----
    unsigned int ks = ((lane >> 4) & 1) ? key[1] : key[0];
    const int idx = 1023 - (int)(ks & 1023u);

    // ---- loss wave-reduce ----
#pragma unroll
    for (int off = 1; off < 64; off <<= 1) part += __shfl_xor(part, off);
    if (lane == 0) lpart[wv] = part;

    // ---- epilogue: z_q gather (exact f32; idx fixed per thread), stores are
    //      2x128B contiguous segments per instruction ----
    const int ch0 = (lane >> 5) * 32;            // channel half
    const int pos = lane & 31;
    const float* erow = embed + idx * 64 + ch0;
    float* orow = out + xbase + (size_t)rowoff + pos + (size_t)ch0 * 4096;
#pragma unroll
    for (int c4 = 0; c4 < 8; c4++) {
        f32x4 ev = *(const f32x4*)(erow + c4 * 4);
#pragma unroll
        for (int j = 0; j < 4; j++)
            orow[(size_t)(c4 * 4 + j) * 4096] = ev[j];
    }

    __syncthreads();                             // lpart visible
    if (t == 0) {
        float s = lpart[0] + lpart[1] + lpart[2] + lpart[3]
                + lpart[4] + lpart[5] + lpart[6] + lpart[7];
        // sum_p dist = sum(z^2) - sum(acc)/512 + 0.125*256
        atomicAdd(loss, (s + 32.0f) * LOSS_SCALE);
    }
}

extern "C" void kernel_launch(void* const* d_in, const int* in_sizes, int n_in,
                              void* d_out, int out_size, void* d_ws, size_t ws_size,
                              hipStream_t stream) {
    const float* x     = (const float*)d_in[0];
    const float* embed = (const float*)d_in[1];
    unsigned char* eb  = (unsigned char*)d_ws;                // 72 KB (stride-72 rows)
    float* c0          = (float*)((char*)d_ws + 73728);       // 4 KB
    float* out  = (float*)d_out;
    float* loss = out + TOTAL_ELEMS;

    vq_prep<<<16, 256, 0, stream>>>(embed, eb, c0, loss);
    vq_main<<<512, 512, 0, stream>>>(x, embed, eb, c0, out, loss);
}